// Round 2
// baseline (246.641 us; speedup 1.0000x reference)
//
#include <hip/hip_runtime.h>
#include <cstdint>
#include <math.h>

typedef unsigned short ushort_t;
typedef __bf16 v8bf __attribute__((ext_vector_type(8)));
typedef float v4f __attribute__((ext_vector_type(4)));

constexpr int B_SZ = 32, NQ = 2048, NK = 2048, DH = 128;
constexpr int BQ = 64, BK = 64;
constexpr int KLD = 136;  // K-tile LDS row stride (bf16 elems): 128+8, 16B-aligned rows
constexpr int VLD = 72;   // Vt-tile LDS row stride
constexpr int PLD = 88;   // P LDS row stride
constexpr float SCALE = 0.08838834764831845f;  // 1/sqrt(128)

// convert 8 contiguous fp32 -> 8 bf16 (RNE), returned as a 16B fragment
__device__ inline v8bf cvt8(const float* __restrict__ p) {
  float4 f0 = *reinterpret_cast<const float4*>(p);
  float4 f1 = *reinterpret_cast<const float4*>(p + 4);
  v8bf r;
  r[0] = (__bf16)f0.x; r[1] = (__bf16)f0.y; r[2] = (__bf16)f0.z; r[3] = (__bf16)f0.w;
  r[4] = (__bf16)f1.x; r[5] = (__bf16)f1.y; r[6] = (__bf16)f1.z; r[7] = (__bf16)f1.w;
  return r;
}

// ---------------- V prepass: Vt[b][d][k] = bf16(V[b][k][d])  (fp32 -> bf16 + transpose) ----
__global__ __launch_bounds__(256) void transpose_v(const float* __restrict__ V,
                                                   ushort_t* __restrict__ Vt) {
  __shared__ __align__(16) ushort_t st[64 * KLD];
  const int b = blockIdx.y, k0 = blockIdx.x * 64, t = threadIdx.x;
  // load 64(k) x 128(d) fp32 tile, convert, stage bf16 (coalesced 2x16B/lane)
  for (int c = 0; c < 4; ++c) {
    const int row = (t >> 4) + 16 * c;
    const int col = (t & 15) * 8;
    v8bf v = cvt8(V + ((size_t)(b * NK + k0 + row)) * DH + col);
    *reinterpret_cast<v8bf*>(&st[row * KLD + col]) = v;
  }
  __syncthreads();
  // write 128(d) x 64(k) bf16, coalesced 16B/lane; gather 8 scalars from LDS column
  for (int c = 0; c < 4; ++c) {
    const int d = (t >> 3) + 32 * c;
    const int kc = (t & 7) * 8;
    alignas(16) ushort_t tmp[8];
    for (int j = 0; j < 8; ++j) tmp[j] = st[(kc + j) * KLD + d];
    *reinterpret_cast<uint4*>(Vt + ((size_t)(b * DH + d)) * NK + k0 + kc) =
        *reinterpret_cast<const uint4*>(tmp);
  }
}

// ---------------- Flash attention forward ----------------
// grid: (NQ/BQ, B); block: 256 = 4 waves; wave w owns q rows [q0+16w, q0+16w+16)
__global__ __launch_bounds__(256, 3) void attn(const float* __restrict__ Q,
                                               const float* __restrict__ K,
                                               const ushort_t* __restrict__ Vt,
                                               const int* __restrict__ vsl,
                                               float* __restrict__ Out) {
  __shared__ __align__(16) ushort_t sK[64 * KLD];      // bf16 K[key][d]
  __shared__ __align__(16) ushort_t sV[DH * VLD];      // bf16 Vt[d][key]
  __shared__ __align__(16) ushort_t sP[4][16 * PLD];   // per-wave bf16 P[qrow][key]

  const int qt = blockIdx.x, b = blockIdx.y;
  const int t = threadIdx.x;
  const int w = t >> 6, lane = t & 63, quad = lane >> 4, l16 = lane & 15;
  const int q0 = qt * BQ;
  const int valid = vsl[b];

  // Q fragments: A[m=l16][k=quad*8+j+32kk], register-resident (fp32 -> bf16 inline)
  v8bf qf[4];
  {
    const float* qp = Q + ((size_t)(b * NQ + q0 + w * 16 + l16)) * DH + quad * 8;
    for (int kk = 0; kk < 4; ++kk) qf[kk] = cvt8(qp + 32 * kk);
  }

  v4f o[8];
  for (int nb = 0; nb < 8; ++nb) o[nb] = (v4f){0.f, 0.f, 0.f, 0.f};
  float m_i[4], l_i[4];
  for (int r = 0; r < 4; ++r) { m_i[r] = -INFINITY; l_i[r] = 0.f; }

  const int nt = (valid + BK - 1) / BK;  // exp(-1e6 - m) underflows to 0 => skip masked tiles

  for (int tile = 0; tile < nt; ++tile) {
    const int k0 = tile * BK;
    // stage K tile 64x128: fp32 load (2x16B/lane), cvt, bf16 LDS write (16B/lane)
    for (int c = 0; c < 4; ++c) {
      const int row = (t >> 4) + 16 * c, col = (t & 15) * 8;
      v8bf v = cvt8(K + ((size_t)(b * NK + k0 + row)) * DH + col);
      *reinterpret_cast<v8bf*>(&sK[row * KLD + col]) = v;
    }
    // stage Vt tile 128x64 bf16 (coalesced 16B/lane)
    for (int c = 0; c < 4; ++c) {
      const int d = (t >> 3) + 32 * c, kc = (t & 7) * 8;
      *reinterpret_cast<uint4*>(&sV[d * VLD + kc]) =
          *reinterpret_cast<const uint4*>(Vt + ((size_t)(b * DH + d)) * NK + k0 + kc);
    }
    __syncthreads();

    // ---- S = Q K^T : 4 col-blocks of 16x16, K-dim 128 = 4 mfma each ----
    float s[4][4];
    for (int cb = 0; cb < 4; ++cb) {
      v4f acc = (v4f){0.f, 0.f, 0.f, 0.f};
      for (int kk = 0; kk < 4; ++kk) {
        // B[k=d][n=key] = K[key][d]: lane reads K row (l16+16cb), 8 d's at quad*8+32kk
        v8bf kf = __builtin_bit_cast(
            v8bf, *reinterpret_cast<const uint4*>(&sK[(l16 + 16 * cb) * KLD + quad * 8 + 32 * kk]));
        acc = __builtin_amdgcn_mfma_f32_16x16x32_bf16(qf[kk], kf, acc, 0, 0, 0);
      }
      const int kidx = k0 + cb * 16 + l16;  // D col = lane&15 -> key index
      const bool okk = kidx < valid;
      for (int r = 0; r < 4; ++r) s[cb][r] = okk ? acc[r] * SCALE : -1e30f;
    }

    // ---- online softmax; q-row (quad*4+r) lives in the quad's 16 lanes ----
    float alpha[4];
    for (int r = 0; r < 4; ++r) {
      float v = fmaxf(fmaxf(s[0][r], s[1][r]), fmaxf(s[2][r], s[3][r]));
      v = fmaxf(v, __shfl_xor(v, 1));
      v = fmaxf(v, __shfl_xor(v, 2));
      v = fmaxf(v, __shfl_xor(v, 4));
      v = fmaxf(v, __shfl_xor(v, 8));
      const float mn = fmaxf(m_i[r], v);
      alpha[r] = __expf(m_i[r] - mn);  // first tile: exp(-inf) = 0
      m_i[r] = mn;
      float rs = 0.f;
      for (int cb = 0; cb < 4; ++cb) {
        const float p = __expf(s[cb][r] - mn);  // masked: exp(~-1e30) == 0
        s[cb][r] = p;
        rs += p;
      }
      rs += __shfl_xor(rs, 1);
      rs += __shfl_xor(rs, 2);
      rs += __shfl_xor(rs, 4);
      rs += __shfl_xor(rs, 8);
      l_i[r] = l_i[r] * alpha[r] + rs;
    }

    // ---- P (C-layout) -> per-wave LDS row-major [16][64] for A-frag reads ----
    ushort_t* sPw = sP[w];
    for (int cb = 0; cb < 4; ++cb)
      for (int r = 0; r < 4; ++r)
        sPw[(quad * 4 + r) * PLD + cb * 16 + l16] =
            __builtin_bit_cast(ushort_t, (__bf16)s[cb][r]);
    __builtin_amdgcn_wave_barrier();  // pin store->load order (per-wave buffer, no __syncthreads)

    // rescale O by alpha
    for (int nb = 0; nb < 8; ++nb)
      for (int r = 0; r < 4; ++r) o[nb][r] *= alpha[r];

    // ---- O += P V : A[m=l16][k=quad*8+j+32kb], B[k=key][n=d] from Vt ----
    v8bf pf[2];
    for (int kb = 0; kb < 2; ++kb)
      pf[kb] = __builtin_bit_cast(
          v8bf, *reinterpret_cast<const uint4*>(&sPw[l16 * PLD + quad * 8 + 32 * kb]));
    for (int nb = 0; nb < 8; ++nb)
      for (int kb = 0; kb < 2; ++kb) {
        v8bf vf = __builtin_bit_cast(
            v8bf, *reinterpret_cast<const uint4*>(&sV[(l16 + 16 * nb) * VLD + quad * 8 + 32 * kb]));
        o[nb] = __builtin_amdgcn_mfma_f32_16x16x32_bf16(pf[kb], vf, o[nb], 0, 0, 0);
      }
    __syncthreads();  // protect sK/sV before next tile's staging
  }

  // ---- epilogue: O / l, store fp32 ----
  for (int r = 0; r < 4; ++r) {
    const float inv = 1.0f / l_i[r];
    float* op = Out + ((size_t)(b * NQ + q0 + w * 16 + quad * 4 + r)) * DH + l16;
    for (int nb = 0; nb < 8; ++nb) op[nb * 16] = o[nb][r] * inv;
  }
}

extern "C" void kernel_launch(void* const* d_in, const int* in_sizes, int n_in,
                              void* d_out, int out_size, void* d_ws, size_t ws_size,
                              hipStream_t stream) {
  const float* Q = (const float*)d_in[0];
  const float* K = (const float*)d_in[1];
  const float* V = (const float*)d_in[2];
  const int* vsl = (const int*)d_in[3];
  float* Out = (float*)d_out;
  ushort_t* Vt = (ushort_t*)d_ws;  // 32*128*2048*2 = 16 MiB bf16 scratch

  dim3 blk(256);
  transpose_v<<<dim3(NK / 64, B_SZ), blk, 0, stream>>>(V, Vt);
  attn<<<dim3(NQ / BQ, B_SZ), blk, 0, stream>>>(Q, K, Vt, vsl, Out);
}